// Round 5
// baseline (165.166 us; speedup 1.0000x reference)
//
#include <hip/hip_runtime.h>
#include <hip/hip_cooperative_groups.h>
namespace cg = cooperative_groups;

// Problem constants
#define BB 8
#define FF 256
#define TT 1024
#define CC 64
constexpr float EPS = 1e-9f;

#define BCF (BB * CC * FF)      // 131072

// ws layout (float offsets)
#define WS_NP 0                 // [512][64]            32768
#define WS_R  32768             // [B][8][128][64]      524288  (b, tq, t', c)
#define WS_FP 557056            // [8][B][64][256]      1048576 (tq-partials)

#define SMEM_FLOATS 9744

// ---------------------------------------------------------------------------
// phase 1: per (b, 16-t tile): mu2/p2 inline, stage x^T, x2, xmu GEMM
// (K-split by wave), softmax over c, write r[b][tq][t'][c] + N partials.
// grid must be 512. (Logic identical to round-3 passA, which passed.)
// ---------------------------------------------------------------------------
__device__ void phase1(const float* __restrict__ x, const float* __restrict__ mu,
                       const float* __restrict__ prec, float* __restrict__ ws,
                       float* smem, int bid, int tid) {
    float (*xt)[260]      = (float(*)[260])smem;              // 16 x 260
    float (*Sred)[16][68] = (float(*)[16][68])(smem + 4160);  // 4 x 16 x 68
    float (*rl)[68]       = (float(*)[68])(smem + 8512);      // 16 x 68
    float *x2s  = smem + 9600;                                // 16
    float *mu2s = smem + 9616;                                // 64
    float *p2s  = smem + 9680;                                // 64

    const int b    = bid >> 6;
    const int tile = bid & 63;
    const int t0   = tile * 16;
    const float* xb = x + (size_t)b * FF * TT;

    // mu2[c], p2[c] inline
    {
        const int c = tid >> 2, q = tid & 3;
        const float* mp = mu + c * FF + q * 64;
        float s = 0.f;
        #pragma unroll
        for (int i = 0; i < 16; ++i) {
            float4 v = *(const float4*)(mp + i * 4);
            s += v.x * v.x + v.y * v.y + v.z * v.z + v.w * v.w;
        }
        s += __shfl_xor(s, 1);
        s += __shfl_xor(s, 2);
        if (q == 0) mu2s[c] = s;
        if (tid < CC) { float p = prec[tid]; p2s[tid] = p * p; }
    }

    // stage x[b][:, t0..t0+16) transposed -> xt[t][f]
    #pragma unroll
    for (int it = 0; it < 4; ++it) {
        const int id = it * 256 + tid;
        const int f = id >> 2, seg = id & 3;
        float4 v = *(const float4*)(xb + f * TT + t0 + seg * 4);
        xt[seg * 4 + 0][f] = v.x;
        xt[seg * 4 + 1][f] = v.y;
        xt[seg * 4 + 2][f] = v.z;
        xt[seg * 4 + 3][f] = v.w;
    }
    __syncthreads();

    // x2[t]
    {
        const int t = tid >> 4, kk = tid & 15;
        float s = 0.f;
        #pragma unroll
        for (int q = 0; q < 16; ++q) { float v = xt[t][kk + 16 * q]; s += v * v; }
        s += __shfl_xor(s, 1);
        s += __shfl_xor(s, 2);
        s += __shfl_xor(s, 4);
        s += __shfl_xor(s, 8);
        if (kk == 0) x2s[t] = s;
    }
    __syncthreads();

    // xmu GEMM: wave g owns f in [g*64, g*64+64)
    {
        const int g = tid >> 6, lane = tid & 63;
        const int tr = lane & 7;
        const int c0 = (lane >> 3) * 8;
        float acc[2][8];
        #pragma unroll
        for (int i = 0; i < 2; ++i)
            #pragma unroll
            for (int j = 0; j < 8; ++j) acc[i][j] = 0.f;

        const float* mupt = mu + (size_t)c0 * FF + g * 64;
        #pragma unroll 4
        for (int kk = 0; kk < 16; ++kk) {
            const int f4 = g * 64 + kk * 4;
            float4 xv0 = *(const float4*)&xt[tr][f4];
            float4 xv1 = *(const float4*)&xt[tr + 8][f4];
            #pragma unroll
            for (int j = 0; j < 8; ++j) {
                float4 mv = *(const float4*)(mupt + j * FF + kk * 4);
                acc[0][j] += xv0.x * mv.x + xv0.y * mv.y + xv0.z * mv.z + xv0.w * mv.w;
                acc[1][j] += xv1.x * mv.x + xv1.y * mv.y + xv1.z * mv.z + xv1.w * mv.w;
            }
        }
        #pragma unroll
        for (int i = 0; i < 2; ++i) {
            *(float4*)&Sred[g][tr + 8 * i][c0] =
                make_float4(acc[i][0], acc[i][1], acc[i][2], acc[i][3]);
            *(float4*)&Sred[g][tr + 8 * i][c0 + 4] =
                make_float4(acc[i][4], acc[i][5], acc[i][6], acc[i][7]);
        }
    }
    __syncthreads();

    // K-split reduce + llk + softmax; write r to LDS and global
    {
        const int t = tid >> 4, kk = tid & 15;
        const int c4 = kk * 4;
        float Sx = 0.f, Sy = 0.f, Sz = 0.f, Sw = 0.f;
        #pragma unroll
        for (int gg = 0; gg < 4; ++gg) {
            float4 v = *(const float4*)&Sred[gg][t][c4];
            Sx += v.x; Sy += v.y; Sz += v.z; Sw += v.w;
        }
        const float x2v = x2s[t];
        float l0 = -p2s[c4 + 0] * (x2v - 2.f * Sx + mu2s[c4 + 0]);
        float l1 = -p2s[c4 + 1] * (x2v - 2.f * Sy + mu2s[c4 + 1]);
        float l2 = -p2s[c4 + 2] * (x2v - 2.f * Sz + mu2s[c4 + 2]);
        float l3 = -p2s[c4 + 3] * (x2v - 2.f * Sw + mu2s[c4 + 3]);
        float m = fmaxf(fmaxf(l0, l1), fmaxf(l2, l3));
        m = fmaxf(m, __shfl_xor(m, 1));
        m = fmaxf(m, __shfl_xor(m, 2));
        m = fmaxf(m, __shfl_xor(m, 4));
        m = fmaxf(m, __shfl_xor(m, 8));
        float e0 = __expf(l0 - m), e1 = __expf(l1 - m);
        float e2 = __expf(l2 - m), e3 = __expf(l3 - m);
        float sum = e0 + e1 + e2 + e3;
        sum += __shfl_xor(sum, 1);
        sum += __shfl_xor(sum, 2);
        sum += __shfl_xor(sum, 4);
        sum += __shfl_xor(sum, 8);
        const float inv = 1.f / sum;
        float4 rv = make_float4(e0 * inv, e1 * inv, e2 * inv, e3 * inv);
        *(float4*)&rl[t][c4] = rv;
        // global write: [b][tq][t'][c]
        const int tq = tile >> 3, tloc = (tile & 7) * 16 + t;
        *(float4*)(ws + WS_R + (((size_t)(b * 8 + tq) * 128) + tloc) * 64 + c4) = rv;
    }
    __syncthreads();

    // N partial
    if (tid < CC) {
        float ns = 0.f;
        #pragma unroll
        for (int t = 0; t < 16; ++t) ns += rl[t][tid];
        ws[WS_NP + (size_t)bid * CC + tid] = ns;
    }
}

// ---------------------------------------------------------------------------
// phase 2: Fpart[tq][b][c][f0..f0+32) over a 128-t chunk (two 64-t sub-iters)
// grid must be 512: b(8) x fsl(8) x tq(8).
// ---------------------------------------------------------------------------
__device__ void phase2(const float* __restrict__ x, float* __restrict__ ws,
                       float* smem, int bid, int tid) {
    float (*xs)[36] = (float(*)[36])smem;          // 64 x 36 (xor-swizzled)
    float (*rs)[68] = (float(*)[68])(smem + 2304); // 64 x 68  [t'][c]
    const int b = bid >> 6, fsl = (bid >> 3) & 7, tq = bid & 7;
    const int f0 = fsl * 32;
    const int t0 = tq * 128;
    const float* xb = x + (size_t)b * FF * TT;
    const float* rb = ws + WS_R + (size_t)(b * 8 + tq) * 128 * 64;

    const int fi = tid & 7, cg = tid >> 3;         // f=f0+fi*4.., c=cg*2+{0,1}
    float a0[4] = {0.f, 0.f, 0.f, 0.f};
    float a1[4] = {0.f, 0.f, 0.f, 0.f};

    for (int sub = 0; sub < 2; ++sub) {
        // stage x tile transposed with XOR swizzle on f-column
        #pragma unroll
        for (int it = 0; it < 2; ++it) {
            const int id = it * 256 + tid;            // [0,512)
            const int ff = id >> 4, seg = id & 15;
            float4 v = *(const float4*)(xb + (f0 + ff) * TT + t0 + sub * 64 + seg * 4);
            #pragma unroll
            for (int k = 0; k < 4; ++k) {
                const int t = seg * 4 + k;
                const float e = (k == 0) ? v.x : (k == 1) ? v.y : (k == 2) ? v.z : v.w;
                xs[t][ff ^ ((t & 7) << 2)] = e;
            }
        }
        // stage r tile: linear coalesced copy (already [t'][c] in global)
        #pragma unroll
        for (int it = 0; it < 4; ++it) {
            const int id = it * 256 + tid;            // [0,1024) float4s
            float4 v = *(const float4*)(rb + (size_t)sub * 4096 + id * 4);
            *(float4*)&rs[id >> 4][(id & 15) * 4] = v;
        }
        __syncthreads();

        #pragma unroll 8
        for (int t = 0; t < 64; ++t) {
            float4 xv = *(const float4*)&xs[t][(fi * 4) ^ ((t & 7) << 2)];
            float2 rv = *(const float2*)&rs[t][cg * 2];
            a0[0] += rv.x * xv.x; a0[1] += rv.x * xv.y;
            a0[2] += rv.x * xv.z; a0[3] += rv.x * xv.w;
            a1[0] += rv.y * xv.x; a1[1] += rv.y * xv.y;
            a1[2] += rv.y * xv.z; a1[3] += rv.y * xv.w;
        }
        __syncthreads();
    }

    float* fp = ws + WS_FP + (size_t)tq * BCF + (size_t)b * CC * FF + f0;
    *(float4*)(fp + (size_t)(cg * 2 + 0) * FF + fi * 4) =
        make_float4(a0[0], a0[1], a0[2], a0[3]);
    *(float4*)(fp + (size_t)(cg * 2 + 1) * FF + fi * 4) =
        make_float4(a1[0], a1[1], a1[2], a1[3]);
}

// ---------------------------------------------------------------------------
// phase 3: out[b][c][f] = (sum_p Fp - N*mu) / (N + eps). grid must be 512.
// ---------------------------------------------------------------------------
__device__ void phase3(const float* __restrict__ mu, const float* __restrict__ ws,
                       float* __restrict__ out, float* smem, int bid, int tid) {
    const int b = bid >> 6, c = bid & 63;
    if (tid < 64) {
        float s = ws[WS_NP + (size_t)(b * 64 + tid) * CC + c];
        #pragma unroll
        for (int k = 1; k < 64; k <<= 1) s += __shfl_xor(s, k);
        if (tid == 0) smem[0] = s;
    }
    __syncthreads();
    const float nr = smem[0];
    const int f = tid;
    const float* fp = ws + WS_FP + ((size_t)b * CC + c) * FF + f;
    float fs = 0.f;
    #pragma unroll
    for (int p = 0; p < 8; ++p) fs += fp[(size_t)p * BCF];
    out[((size_t)b * CC + c) * FF + f] = (fs - nr * mu[c * FF + f]) / (nr + EPS);
}

// ---------------------------------------------------------------------------
// Cooperative mono-kernel (512 blocks, needs only 2 blocks/CU co-resident)
// ---------------------------------------------------------------------------
__global__ __launch_bounds__(256, 2) void lde_coop(
        const float* __restrict__ x, const float* __restrict__ mu,
        const float* __restrict__ prec, float* __restrict__ ws,
        float* __restrict__ out) {
    __shared__ float smem[SMEM_FLOATS];
    cg::grid_group grid = cg::this_grid();
    phase1(x, mu, prec, ws, smem, blockIdx.x, threadIdx.x);
    grid.sync();
    phase2(x, ws, smem, blockIdx.x, threadIdx.x);
    grid.sync();
    phase3(mu, ws, out, smem, blockIdx.x, threadIdx.x);
}

// ---------------------------------------------------------------------------
// Fallback path: same phases as separate kernels
// ---------------------------------------------------------------------------
__global__ __launch_bounds__(256) void k_phase1(const float* __restrict__ x,
                                               const float* __restrict__ mu,
                                               const float* __restrict__ prec,
                                               float* __restrict__ ws) {
    __shared__ float smem[SMEM_FLOATS];
    phase1(x, mu, prec, ws, smem, blockIdx.x, threadIdx.x);
}
__global__ __launch_bounds__(256) void k_phase2(const float* __restrict__ x,
                                               float* __restrict__ ws) {
    __shared__ float smem[6656];
    phase2(x, ws, smem, blockIdx.x, threadIdx.x);
}
__global__ __launch_bounds__(256) void k_phase3(const float* __restrict__ mu,
                                               const float* __restrict__ ws,
                                               float* __restrict__ out) {
    __shared__ float smem[64];
    phase3(mu, ws, out, smem, blockIdx.x, threadIdx.x);
}

extern "C" void kernel_launch(void* const* d_in, const int* in_sizes, int n_in,
                              void* d_out, int out_size, void* d_ws, size_t ws_size,
                              hipStream_t stream) {
    const float* x    = (const float*)d_in[0];
    const float* mu   = (const float*)d_in[1];
    const float* prec = (const float*)d_in[2];
    float* out = (float*)d_out;
    float* ws  = (float*)d_ws;

    void* kargs[] = {(void*)&x, (void*)&mu, (void*)&prec, (void*)&ws, (void*)&out};
    hipError_t err = hipLaunchCooperativeKernel((const void*)lde_coop, dim3(512),
                                                dim3(256), kargs, 0, stream);
    if (err != hipSuccess) {
        (void)hipGetLastError();   // clear sticky error
        k_phase1<<<512, 256, 0, stream>>>(x, mu, prec, ws);
        k_phase2<<<512, 256, 0, stream>>>(x, ws);
        k_phase3<<<512, 256, 0, stream>>>(mu, ws, out);
    }
}

// Round 6
// 43.491 us; speedup vs baseline: 3.7977x; 3.7977x over previous
//
#include <hip/hip_runtime.h>

// Problem constants
#define BB 8
#define FF 256
#define TT 1024
#define CC 64
constexpr float EPS = 1e-9f;

#define BCF (BB * CC * FF)      // 131072

// ws layout (float offsets)
#define WS_NP 0                 // [1024][64]           65536
#define WS_R  65536             // [B][16][64][64]      524288  (b, tq, t', c)
#define WS_FP 589824            // [16][B][64][256]     2097152 (tq-partials)

// ---------------------------------------------------------------------------
// passA: per (b, 8-t tile): mu2/p2 inline, stage x^T, x2, xmu GEMM (K-split
// by wave), softmax over c, write r[b][tq][t'][c] + N partials.
// grid = 1024 (b(8) x tile(128)), 4 blocks/CU.
// ---------------------------------------------------------------------------
__global__ __launch_bounds__(256, 4) void passA_kernel(
        const float* __restrict__ x, const float* __restrict__ mu,
        const float* __restrict__ prec, float* __restrict__ ws) {
    __shared__ __align__(16) float xt[8][260];       // [t][f]
    __shared__ __align__(16) float Sred[4][8][68];   // K-split partials
    __shared__ __align__(16) float rl[8][68];        // r[t][c]
    __shared__ float x2s[8];
    __shared__ float mu2s[CC], p2s[CC];

    const int tid = threadIdx.x;
    const int b    = blockIdx.x >> 7;
    const int tile = blockIdx.x & 127;
    const int t0   = tile * 8;
    const float* xb = x + (size_t)b * FF * TT;

    // mu2[c], p2[c] inline
    {
        const int c = tid >> 2, q = tid & 3;
        const float* mp = mu + c * FF + q * 64;
        float s = 0.f;
        #pragma unroll
        for (int i = 0; i < 16; ++i) {
            float4 v = *(const float4*)(mp + i * 4);
            s += v.x * v.x + v.y * v.y + v.z * v.z + v.w * v.w;
        }
        s += __shfl_xor(s, 1);
        s += __shfl_xor(s, 2);
        if (q == 0) mu2s[c] = s;
        if (tid < CC) { float p = prec[tid]; p2s[tid] = p * p; }
    }

    // stage x[b][:, t0..t0+8) transposed -> xt[t][f]
    #pragma unroll
    for (int it = 0; it < 2; ++it) {
        const int id = it * 256 + tid;           // [0,512)
        const int f = id >> 1, seg = id & 1;
        float4 v = *(const float4*)(xb + f * TT + t0 + seg * 4);
        xt[seg * 4 + 0][f] = v.x;
        xt[seg * 4 + 1][f] = v.y;
        xt[seg * 4 + 2][f] = v.z;
        xt[seg * 4 + 3][f] = v.w;
    }
    __syncthreads();

    // x2[t]: 32 lanes per t-row
    {
        const int t = tid >> 5, kk = tid & 31;
        float s = 0.f;
        #pragma unroll
        for (int q = 0; q < 8; ++q) { float v = xt[t][kk + 32 * q]; s += v * v; }
        s += __shfl_xor(s, 1);
        s += __shfl_xor(s, 2);
        s += __shfl_xor(s, 4);
        s += __shfl_xor(s, 8);
        s += __shfl_xor(s, 16);
        if (kk == 0) x2s[t] = s;
    }

    // xmu GEMM: wave g owns f in [g*64, g*64+64); lane: tr=t (8), c0=8c
    {
        const int g = tid >> 6, lane = tid & 63;
        const int tr = lane & 7;
        const int c0 = (lane >> 3) * 8;
        float acc[8] = {0.f, 0.f, 0.f, 0.f, 0.f, 0.f, 0.f, 0.f};
        const float* mupt = mu + (size_t)c0 * FF + g * 64;
        #pragma unroll 4
        for (int kk = 0; kk < 16; ++kk) {
            float4 xv = *(const float4*)&xt[tr][g * 64 + kk * 4];
            #pragma unroll
            for (int j = 0; j < 8; ++j) {
                float4 mv = *(const float4*)(mupt + j * FF + kk * 4);
                acc[j] += xv.x * mv.x + xv.y * mv.y + xv.z * mv.z + xv.w * mv.w;
            }
        }
        *(float4*)&Sred[g][tr][c0]     = make_float4(acc[0], acc[1], acc[2], acc[3]);
        *(float4*)&Sred[g][tr][c0 + 4] = make_float4(acc[4], acc[5], acc[6], acc[7]);
    }
    __syncthreads();

    // K-split reduce + llk + softmax over c (32 lanes per t, 2 c per lane)
    {
        const int t = tid >> 5, kk = tid & 31;
        const int c2 = kk * 2;
        float Sx = 0.f, Sy = 0.f;
        #pragma unroll
        for (int gg = 0; gg < 4; ++gg) {
            float2 v = *(const float2*)&Sred[gg][t][c2];
            Sx += v.x; Sy += v.y;
        }
        const float x2v = x2s[t];
        float l0 = -p2s[c2 + 0] * (x2v - 2.f * Sx + mu2s[c2 + 0]);
        float l1 = -p2s[c2 + 1] * (x2v - 2.f * Sy + mu2s[c2 + 1]);
        float m = fmaxf(l0, l1);
        m = fmaxf(m, __shfl_xor(m, 1));
        m = fmaxf(m, __shfl_xor(m, 2));
        m = fmaxf(m, __shfl_xor(m, 4));
        m = fmaxf(m, __shfl_xor(m, 8));
        m = fmaxf(m, __shfl_xor(m, 16));
        float e0 = __expf(l0 - m), e1 = __expf(l1 - m);
        float sum = e0 + e1;
        sum += __shfl_xor(sum, 1);
        sum += __shfl_xor(sum, 2);
        sum += __shfl_xor(sum, 4);
        sum += __shfl_xor(sum, 8);
        sum += __shfl_xor(sum, 16);
        const float inv = 1.f / sum;
        const float r0 = e0 * inv, r1 = e1 * inv;
        rl[t][c2] = r0;
        rl[t][c2 + 1] = r1;
        // global write: [b][tq][t'][c], tq = t_global/64, t' = t_global%64
        const int tq = tile >> 3, tloc = (tile & 7) * 8 + t;
        *(float2*)(ws + WS_R + (((size_t)(b * 16 + tq) * 64) + tloc) * 64 + c2) =
            make_float2(r0, r1);
    }
    __syncthreads();

    // N partial
    if (tid < CC) {
        float ns = 0.f;
        #pragma unroll
        for (int t = 0; t < 8; ++t) ns += rl[t][tid];
        ws[WS_NP + (size_t)blockIdx.x * CC + tid] = ns;
    }
}

// ---------------------------------------------------------------------------
// passB: Fpart[tq][b][c][f0..f0+32) = sum_{t in 64-chunk} r[t][c]*x[f][t]
// grid = 1024: b(8) x fsl(8) x tq(16). 2c x 4f per thread.
// ---------------------------------------------------------------------------
__global__ __launch_bounds__(256, 4) void passB_kernel(
        const float* __restrict__ x, float* __restrict__ ws) {
    __shared__ __align__(16) float xs[64][36];   // [t][f'] xor-swizzled
    __shared__ __align__(16) float rs[64][68];   // [t'][c]
    const int tid = threadIdx.x;
    const int bid = blockIdx.x;
    const int b = bid >> 7, fsl = (bid >> 4) & 7, tq = bid & 15;
    const int f0 = fsl * 32;
    const int t0 = tq * 64;
    const float* xb = x + (size_t)b * FF * TT;
    const float* rb = ws + WS_R + (size_t)(b * 16 + tq) * 64 * 64;

    // stage x tile transposed with XOR swizzle on f-column
    #pragma unroll
    for (int it = 0; it < 2; ++it) {
        const int id = it * 256 + tid;            // [0,512)
        const int ff = id >> 4, seg = id & 15;
        float4 v = *(const float4*)(xb + (f0 + ff) * TT + t0 + seg * 4);
        #pragma unroll
        for (int k = 0; k < 4; ++k) {
            const int t = seg * 4 + k;
            const float e = (k == 0) ? v.x : (k == 1) ? v.y : (k == 2) ? v.z : v.w;
            xs[t][ff ^ ((t & 7) << 2)] = e;
        }
    }
    // stage r tile: linear coalesced copy (already [t'][c] in global)
    #pragma unroll
    for (int it = 0; it < 4; ++it) {
        const int id = it * 256 + tid;            // [0,1024) float4s
        float4 v = *(const float4*)(rb + id * 4);
        *(float4*)&rs[id >> 4][(id & 15) * 4] = v;
    }
    __syncthreads();

    const int fi = tid & 7, cg = tid >> 3;        // f=f0+fi*4.., c=cg*2+{0,1}
    float a0[4] = {0.f, 0.f, 0.f, 0.f};
    float a1[4] = {0.f, 0.f, 0.f, 0.f};
    #pragma unroll 8
    for (int t = 0; t < 64; ++t) {
        float4 xv = *(const float4*)&xs[t][(fi * 4) ^ ((t & 7) << 2)];
        float2 rv = *(const float2*)&rs[t][cg * 2];
        a0[0] += rv.x * xv.x; a0[1] += rv.x * xv.y;
        a0[2] += rv.x * xv.z; a0[3] += rv.x * xv.w;
        a1[0] += rv.y * xv.x; a1[1] += rv.y * xv.y;
        a1[2] += rv.y * xv.z; a1[3] += rv.y * xv.w;
    }

    float* fp = ws + WS_FP + (size_t)tq * BCF + (size_t)b * CC * FF + f0;
    *(float4*)(fp + (size_t)(cg * 2 + 0) * FF + fi * 4) =
        make_float4(a0[0], a0[1], a0[2], a0[3]);
    *(float4*)(fp + (size_t)(cg * 2 + 1) * FF + fi * 4) =
        make_float4(a1[0], a1[1], a1[2], a1[3]);
}

// ---------------------------------------------------------------------------
// final: out[b][c][f] = (sum_p Fp - N*mu) / (N + eps). grid = 512 (b,c).
// ---------------------------------------------------------------------------
__global__ __launch_bounds__(256, 4) void final_kernel(
        const float* __restrict__ mu, const float* __restrict__ ws,
        float* __restrict__ out) {
    __shared__ float nsh[4];
    const int tid = threadIdx.x;
    const int b = blockIdx.x >> 6, c = blockIdx.x & 63;

    // N: reduce 128 tile-partials
    float s = 0.f;
    if (tid < 128) s = ws[WS_NP + (size_t)(b * 128 + tid) * CC + c];
    s += __shfl_xor(s, 1);
    s += __shfl_xor(s, 2);
    s += __shfl_xor(s, 4);
    s += __shfl_xor(s, 8);
    s += __shfl_xor(s, 16);
    s += __shfl_xor(s, 32);
    if ((tid & 63) == 0) nsh[tid >> 6] = s;
    __syncthreads();
    const float nr = nsh[0] + nsh[1] + nsh[2] + nsh[3];

    const int f = tid;
    const float* fp = ws + WS_FP + ((size_t)b * CC + c) * FF + f;
    float fs = 0.f;
    #pragma unroll
    for (int p = 0; p < 16; ++p) fs += fp[(size_t)p * BCF];
    out[((size_t)b * CC + c) * FF + f] = (fs - nr * mu[c * FF + f]) / (nr + EPS);
}

extern "C" void kernel_launch(void* const* d_in, const int* in_sizes, int n_in,
                              void* d_out, int out_size, void* d_ws, size_t ws_size,
                              hipStream_t stream) {
    const float* x    = (const float*)d_in[0];
    const float* mu   = (const float*)d_in[1];
    const float* prec = (const float*)d_in[2];
    float* out = (float*)d_out;
    float* ws  = (float*)d_ws;

    passA_kernel<<<1024, 256, 0, stream>>>(x, mu, prec, ws);
    passB_kernel<<<1024, 256, 0, stream>>>(x, ws);
    final_kernel<<<512, 256, 0, stream>>>(mu, ws, out);
}

// Round 7
// 34.464 us; speedup vs baseline: 4.7924x; 1.2619x over previous
//
#include <hip/hip_runtime.h>

// Problem constants
#define BB 8
#define FF 256
#define TT 1024
#define CC 64
constexpr float EPS = 1e-9f;

#define BCF (BB * CC * FF)      // 131072

// ws layout (float offsets)
#define WS_NP 0                 // [512][64]            32768
#define WS_R  32768             // [B][8][128][64]      524288  (b, tq, t', c)
#define WS_FP 557056            // [8][B][64][256]      1048576 (tq-partials)

// ---------------------------------------------------------------------------
// phase 1: per (b, 16-t tile): mu2/p2 inline, stage x^T, x2, xmu GEMM
// (K-split by wave), softmax over c, write r[b][tq][t'][c] + N partials.
// grid = 512 (b(8) x tile(64)). [round-3/round-5 verified logic]
// ---------------------------------------------------------------------------
__global__ __launch_bounds__(256, 2) void k_phase1(
        const float* __restrict__ x, const float* __restrict__ mu,
        const float* __restrict__ prec, float* __restrict__ ws) {
    __shared__ __align__(16) float xt[16][260];       // [t][f]
    __shared__ __align__(16) float Sred[4][16][68];   // K-split partials
    __shared__ __align__(16) float rl[16][68];        // r[t][c]
    __shared__ float x2s[16];
    __shared__ float mu2s[CC], p2s[CC];

    const int tid = threadIdx.x;
    const int b    = blockIdx.x >> 6;
    const int tile = blockIdx.x & 63;
    const int t0   = tile * 16;
    const float* xb = x + (size_t)b * FF * TT;

    // mu2[c], p2[c] inline
    {
        const int c = tid >> 2, q = tid & 3;
        const float* mp = mu + c * FF + q * 64;
        float s = 0.f;
        #pragma unroll
        for (int i = 0; i < 16; ++i) {
            float4 v = *(const float4*)(mp + i * 4);
            s += v.x * v.x + v.y * v.y + v.z * v.z + v.w * v.w;
        }
        s += __shfl_xor(s, 1);
        s += __shfl_xor(s, 2);
        if (q == 0) mu2s[c] = s;
        if (tid < CC) { float p = prec[tid]; p2s[tid] = p * p; }
    }

    // stage x[b][:, t0..t0+16) transposed -> xt[t][f]
    #pragma unroll
    for (int it = 0; it < 4; ++it) {
        const int id = it * 256 + tid;
        const int f = id >> 2, seg = id & 3;
        float4 v = *(const float4*)(xb + f * TT + t0 + seg * 4);
        xt[seg * 4 + 0][f] = v.x;
        xt[seg * 4 + 1][f] = v.y;
        xt[seg * 4 + 2][f] = v.z;
        xt[seg * 4 + 3][f] = v.w;
    }
    __syncthreads();

    // x2[t]
    {
        const int t = tid >> 4, kk = tid & 15;
        float s = 0.f;
        #pragma unroll
        for (int q = 0; q < 16; ++q) { float v = xt[t][kk + 16 * q]; s += v * v; }
        s += __shfl_xor(s, 1);
        s += __shfl_xor(s, 2);
        s += __shfl_xor(s, 4);
        s += __shfl_xor(s, 8);
        if (kk == 0) x2s[t] = s;
    }
    __syncthreads();

    // xmu GEMM: wave g owns f in [g*64, g*64+64)
    {
        const int g = tid >> 6, lane = tid & 63;
        const int tr = lane & 7;
        const int c0 = (lane >> 3) * 8;
        float acc[2][8];
        #pragma unroll
        for (int i = 0; i < 2; ++i)
            #pragma unroll
            for (int j = 0; j < 8; ++j) acc[i][j] = 0.f;

        const float* mupt = mu + (size_t)c0 * FF + g * 64;
        #pragma unroll 4
        for (int kk = 0; kk < 16; ++kk) {
            const int f4 = g * 64 + kk * 4;
            float4 xv0 = *(const float4*)&xt[tr][f4];
            float4 xv1 = *(const float4*)&xt[tr + 8][f4];
            #pragma unroll
            for (int j = 0; j < 8; ++j) {
                float4 mv = *(const float4*)(mupt + j * FF + kk * 4);
                acc[0][j] += xv0.x * mv.x + xv0.y * mv.y + xv0.z * mv.z + xv0.w * mv.w;
                acc[1][j] += xv1.x * mv.x + xv1.y * mv.y + xv1.z * mv.z + xv1.w * mv.w;
            }
        }
        #pragma unroll
        for (int i = 0; i < 2; ++i) {
            *(float4*)&Sred[g][tr + 8 * i][c0] =
                make_float4(acc[i][0], acc[i][1], acc[i][2], acc[i][3]);
            *(float4*)&Sred[g][tr + 8 * i][c0 + 4] =
                make_float4(acc[i][4], acc[i][5], acc[i][6], acc[i][7]);
        }
    }
    __syncthreads();

    // K-split reduce + llk + softmax; write r to LDS and global
    {
        const int t = tid >> 4, kk = tid & 15;
        const int c4 = kk * 4;
        float Sx = 0.f, Sy = 0.f, Sz = 0.f, Sw = 0.f;
        #pragma unroll
        for (int gg = 0; gg < 4; ++gg) {
            float4 v = *(const float4*)&Sred[gg][t][c4];
            Sx += v.x; Sy += v.y; Sz += v.z; Sw += v.w;
        }
        const float x2v = x2s[t];
        float l0 = -p2s[c4 + 0] * (x2v - 2.f * Sx + mu2s[c4 + 0]);
        float l1 = -p2s[c4 + 1] * (x2v - 2.f * Sy + mu2s[c4 + 1]);
        float l2 = -p2s[c4 + 2] * (x2v - 2.f * Sz + mu2s[c4 + 2]);
        float l3 = -p2s[c4 + 3] * (x2v - 2.f * Sw + mu2s[c4 + 3]);
        float m = fmaxf(fmaxf(l0, l1), fmaxf(l2, l3));
        m = fmaxf(m, __shfl_xor(m, 1));
        m = fmaxf(m, __shfl_xor(m, 2));
        m = fmaxf(m, __shfl_xor(m, 4));
        m = fmaxf(m, __shfl_xor(m, 8));
        float e0 = __expf(l0 - m), e1 = __expf(l1 - m);
        float e2 = __expf(l2 - m), e3 = __expf(l3 - m);
        float sum = e0 + e1 + e2 + e3;
        sum += __shfl_xor(sum, 1);
        sum += __shfl_xor(sum, 2);
        sum += __shfl_xor(sum, 4);
        sum += __shfl_xor(sum, 8);
        const float inv = 1.f / sum;
        float4 rv = make_float4(e0 * inv, e1 * inv, e2 * inv, e3 * inv);
        *(float4*)&rl[t][c4] = rv;
        // global write: [b][tq][t'][c], tq = t_global/128, t' = t_global%128
        const int tq = tile >> 3, tloc = (tile & 7) * 16 + t;
        *(float4*)(ws + WS_R + (((size_t)(b * 8 + tq) * 128) + tloc) * 64 + c4) = rv;
    }
    __syncthreads();

    // N partial
    if (tid < CC) {
        float ns = 0.f;
        #pragma unroll
        for (int t = 0; t < 16; ++t) ns += rl[t][tid];
        ws[WS_NP + (size_t)blockIdx.x * CC + tid] = ns;
    }
}

// ---------------------------------------------------------------------------
// phase 2: Fpart[tq][b][c][f0..f0+32) over a 128-t chunk (two 64-t sub-iters)
// grid = 512: b(8) x fsl(8) x tq(8). [round-5 verified logic]
// ---------------------------------------------------------------------------
__global__ __launch_bounds__(256, 2) void k_phase2(
        const float* __restrict__ x, float* __restrict__ ws) {
    __shared__ __align__(16) float xs[64][36];   // [t][f'] xor-swizzled
    __shared__ __align__(16) float rs[64][68];   // [t'][c]
    const int tid = threadIdx.x;
    const int bid = blockIdx.x;
    const int b = bid >> 6, fsl = (bid >> 3) & 7, tq = bid & 7;
    const int f0 = fsl * 32;
    const int t0 = tq * 128;
    const float* xb = x + (size_t)b * FF * TT;
    const float* rb = ws + WS_R + (size_t)(b * 8 + tq) * 128 * 64;

    const int fi = tid & 7, cg = tid >> 3;       // f=f0+fi*4.., c=cg*2+{0,1}
    float a0[4] = {0.f, 0.f, 0.f, 0.f};
    float a1[4] = {0.f, 0.f, 0.f, 0.f};

    for (int sub = 0; sub < 2; ++sub) {
        // stage x tile transposed with XOR swizzle on f-column
        #pragma unroll
        for (int it = 0; it < 2; ++it) {
            const int id = it * 256 + tid;        // [0,512)
            const int ff = id >> 4, seg = id & 15;
            float4 v = *(const float4*)(xb + (f0 + ff) * TT + t0 + sub * 64 + seg * 4);
            #pragma unroll
            for (int k = 0; k < 4; ++k) {
                const int t = seg * 4 + k;
                const float e = (k == 0) ? v.x : (k == 1) ? v.y : (k == 2) ? v.z : v.w;
                xs[t][ff ^ ((t & 7) << 2)] = e;
            }
        }
        // stage r tile: linear coalesced copy (already [t'][c] in global)
        #pragma unroll
        for (int it = 0; it < 4; ++it) {
            const int id = it * 256 + tid;        // [0,1024) float4s
            float4 v = *(const float4*)(rb + (size_t)sub * 4096 + id * 4);
            *(float4*)&rs[id >> 4][(id & 15) * 4] = v;
        }
        __syncthreads();

        #pragma unroll 8
        for (int t = 0; t < 64; ++t) {
            float4 xv = *(const float4*)&xs[t][(fi * 4) ^ ((t & 7) << 2)];
            float2 rv = *(const float2*)&rs[t][cg * 2];
            a0[0] += rv.x * xv.x; a0[1] += rv.x * xv.y;
            a0[2] += rv.x * xv.z; a0[3] += rv.x * xv.w;
            a1[0] += rv.y * xv.x; a1[1] += rv.y * xv.y;
            a1[2] += rv.y * xv.z; a1[3] += rv.y * xv.w;
        }
        __syncthreads();
    }

    float* fp = ws + WS_FP + (size_t)tq * BCF + (size_t)b * CC * FF + f0;
    *(float4*)(fp + (size_t)(cg * 2 + 0) * FF + fi * 4) =
        make_float4(a0[0], a0[1], a0[2], a0[3]);
    *(float4*)(fp + (size_t)(cg * 2 + 1) * FF + fi * 4) =
        make_float4(a1[0], a1[1], a1[2], a1[3]);
}

// ---------------------------------------------------------------------------
// phase 3: out[b][c][f] = (sum_p Fp - N*mu) / (N + eps). grid = 512 (b,c).
// ---------------------------------------------------------------------------
__global__ __launch_bounds__(256, 2) void k_phase3(
        const float* __restrict__ mu, const float* __restrict__ ws,
        float* __restrict__ out) {
    __shared__ float nsh[1];
    const int tid = threadIdx.x;
    const int b = blockIdx.x >> 6, c = blockIdx.x & 63;
    if (tid < 64) {
        float s = ws[WS_NP + (size_t)(b * 64 + tid) * CC + c];
        #pragma unroll
        for (int k = 1; k < 64; k <<= 1) s += __shfl_xor(s, k);
        if (tid == 0) nsh[0] = s;
    }
    __syncthreads();
    const float nr = nsh[0];
    const int f = tid;
    const float* fp = ws + WS_FP + ((size_t)b * CC + c) * FF + f;
    float fs = 0.f;
    #pragma unroll
    for (int p = 0; p < 8; ++p) fs += fp[(size_t)p * BCF];
    out[((size_t)b * CC + c) * FF + f] = (fs - nr * mu[c * FF + f]) / (nr + EPS);
}

extern "C" void kernel_launch(void* const* d_in, const int* in_sizes, int n_in,
                              void* d_out, int out_size, void* d_ws, size_t ws_size,
                              hipStream_t stream) {
    const float* x    = (const float*)d_in[0];
    const float* mu   = (const float*)d_in[1];
    const float* prec = (const float*)d_in[2];
    float* out = (float*)d_out;
    float* ws  = (float*)d_ws;

    k_phase1<<<512, 256, 0, stream>>>(x, mu, prec, ws);
    k_phase2<<<512, 256, 0, stream>>>(x, ws);
    k_phase3<<<512, 256, 0, stream>>>(mu, ws, out);
}